// Round 5
// baseline (1288.243 us; speedup 1.0000x reference)
//
#include <hip/hip_runtime.h>
#include <hip/hip_bf16.h>

typedef _Float16 f16;
typedef __attribute__((ext_vector_type(8))) _Float16 f16x8;
typedef __attribute__((ext_vector_type(4))) _Float16 f16x4;
typedef __attribute__((ext_vector_type(4))) float f32x4;

// ---------- small device helpers ----------
__device__ __forceinline__ float geluf(float x) {
    return 0.5f * x * (1.0f + erff(x * 0.70710678118654752440f));
}
__device__ __forceinline__ float sigmf(float x) { return 1.0f / (1.0f + __expf(-x)); }

// Sizes (fixed by the problem)
#define NB 16
#define NC 128
#define NH 128
#define NW 128
#define PLANE (NH * NW)          // 16384
#define NSTAT 262144.0f          // B*H*W per-channel BN count

// Device-global staging (no workspace-size assumptions).
// g_Wc   : [tap(9)][chunk(4)][co(128)][ci32]          (raw f16)
// g_Wsc  : [chunk(4)][co(128)][ci32]                  (raw f16)
// g_W2   : [chunk(4)][co(128)][ci32]
// g_Wcb  : [b(16)][tap(9)][chunk(4)][co(128)][ci32]   (mod-folded)
// g_Wscb : [b(16)][chunk(4)][co(128)][ci32]           (mod-folded)
// g_xT   : [b][h][chunk(4)][wslot(130)][ci32]         (raw x, f16; slots 0,129 zero)
// g_y1T  : [b][h][cog(4)][w(128)][co32]               (conv1 out, f16)
__device__ __align__(16) f16 g_Wc[9 * 4 * 128 * 32];
__device__ __align__(16) f16 g_Wsc[4 * 128 * 32];
__device__ __align__(16) f16 g_W2[4 * 128 * 32];
__device__ __align__(16) f16 g_Wcb[(size_t)16 * 9 * 4 * 128 * 32];
__device__ __align__(16) f16 g_Wscb[(size_t)16 * 4 * 128 * 32];
__device__ __align__(16) f16 g_xT[(size_t)16 * 128 * 4 * 130 * 32];
__device__ __align__(16) f16 g_y1T[(size_t)16 * 128 * 4 * 128 * 32];
__device__ __align__(16) f16 g_zrow[4160];   // zero-init (.bss), never written
// reduction buffers for the folded spatial path
__device__ float g_red[5][16][128];          // full,row0,row127,col0,col127
__device__ float g_corn[4][16][128];         // x00,x0e,xe0,xee

// ---------- K0: convert weights to f16 MFMA layout; zero g_red ----------
__global__ __launch_bounds__(256) void k_wprep(const float* __restrict__ c1w,
                                               const float* __restrict__ scw,
                                               const float* __restrict__ c2w) {
    int i = blockIdx.x * 256 + threadIdx.x;
    if (i < 10240) ((float*)g_red)[i] = 0.0f;
    if (i < 147456) {                       // 9*4*128*32
        int tap = i / 16384;
        int rem = i - tap * 16384;
        int chunk = rem >> 12;
        int r2 = rem & 4095;
        int co = r2 >> 5;
        int cil = r2 & 31;
        int ci = chunk * 32 + cil;
        g_Wc[i] = (f16)c1w[((size_t)co * 128 + ci) * 9 + tap];
    } else if (i < 163840) {                // + 4*128*32
        int j = i - 147456;
        int chunk = j >> 12;
        int r2 = j & 4095;
        int co = r2 >> 5;
        int cil = r2 & 31;
        g_Wsc[j] = (f16)scw[(size_t)co * 128 + chunk * 32 + cil];
    } else if (i < 180224) {                // + 4*128*32
        int j = i - 163840;
        int chunk = j >> 12;
        int r2 = j & 4095;
        int co = r2 >> 5;
        int cil = j & 31;
        g_W2[j] = (f16)c2w[(size_t)co * 128 + chunk * 32 + cil];
    }
}

// ---------- K1: partial dce @ W1, K-split over 128 blocks, atomicAdd into dh ----------
__global__ __launch_bounds__(256) void k_dce1(const float* __restrict__ dce,
                                              const float* __restrict__ W1,
                                              float* __restrict__ dh) {
    int ks = blockIdx.x;          // 128 slices of 100 k
    int kbase = ks * 100;
    int t = threadIdx.x;
    __shared__ float sdce[16][100];
    for (int e = t; e < 1600; e += 256) {
        int bb = e / 100, k = e - bb * 100;
        sdce[bb][k] = dce[(size_t)bb * 12800 + kbase + k];
    }
    __syncthreads();
    int j = t & 127;
    int bg = t >> 7;
    float accs[8];
#pragma unroll
    for (int i = 0; i < 8; ++i) accs[i] = 0.0f;
    for (int k = 0; k < 100; ++k) {
        float wv = W1[((size_t)(kbase + k)) * 128 + j];
#pragma unroll
        for (int bb = 0; bb < 8; ++bb) accs[bb] += sdce[bg * 8 + bb][k] * wv;
    }
#pragma unroll
    for (int bb = 0; bb < 8; ++bb)
        atomicAdd(&dh[(bg * 8 + bb) * 128 + j], accs[bb]);
}

// ---------- K2: dce_feat = gelu(dh + b1) @ W2 + b2, [16,128] ----------
__global__ __launch_bounds__(128) void k_dce2(const float* __restrict__ dh,
                                              const float* __restrict__ b1,
                                              const float* __restrict__ W2,
                                              const float* __restrict__ b2,
                                              float* __restrict__ feat) {
    int b = blockIdx.x, j = threadIdx.x;
    __shared__ float sh[128];
    sh[j] = geluf(dh[b * 128 + j] + b1[j]);
    __syncthreads();
    float acc = b2[j];
    for (int k = 0; k < 128; ++k) acc += sh[k] * W2[k * 128 + j];
    feat[b * 128 + j] = acc;
}

// ---------- K3: xprep — raw xT transpose + folded spatial reductions ----------
__global__ __launch_bounds__(256) void k_xprep(const float* __restrict__ x) {
    int bid = blockIdx.x;  // b*128 + h
    int h = bid & 127;
    int b = bid >> 7;
    int t = threadIdx.x;
    int w4 = t & 31;
    __shared__ float sx[32][133];

    for (int chunk = 0; chunk < 4; ++chunk) {
        __syncthreads();
#pragma unroll
        for (int it = 0; it < 4; ++it) {
            int ci = it * 8 + (t >> 5);
            int cig = chunk * 32 + ci;
            float4 v = *(const float4*)&x[(((size_t)b * 128 + cig) * 128 + h) * 128 + w4 * 4];
            sx[ci][w4 * 4 + 0] = v.x;
            sx[ci][w4 * 4 + 1] = v.y;
            sx[ci][w4 * 4 + 2] = v.z;
            sx[ci][w4 * 4 + 3] = v.w;
            // folded spatial reductions
            float s4 = v.x + v.y + v.z + v.w;
#pragma unroll
            for (int o = 1; o < 32; o <<= 1) s4 += __shfl_xor(s4, o);
            if (w4 == 0) {
                atomicAdd(&g_red[0][b][cig], s4);
                if (h == 0) atomicAdd(&g_red[1][b][cig], s4);
                if (h == 127) atomicAdd(&g_red[2][b][cig], s4);
                atomicAdd(&g_red[3][b][cig], v.x);
                if (h == 0) g_corn[0][b][cig] = v.x;
                if (h == 127) g_corn[2][b][cig] = v.x;
            }
            if (w4 == 31) {
                atomicAdd(&g_red[4][b][cig], v.w);
                if (h == 0) g_corn[1][b][cig] = v.w;
                if (h == 127) g_corn[3][b][cig] = v.w;
            }
        }
        __syncthreads();
        f16* dstc = g_xT + (((size_t)(b * 128 + h)) * 4 + chunk) * 4160;
        for (int g = t; g < 520; g += 256) {
            int s = g >> 2, c8 = g & 3;
            f16x8 o;
            if (s == 0 || s == 129) {
#pragma unroll
                for (int j = 0; j < 8; ++j) o[j] = (f16)0.f;
            } else {
#pragma unroll
                for (int j = 0; j < 8; ++j) o[j] = (f16)sx[c8 * 8 + j][s - 1];
            }
            *(f16x8*)(dstc + s * 32 + c8 * 8) = o;
        }
    }
}

// ---------- K4: spatial finalize + SE modulation -> mod_w [16,128] ----------
__global__ __launch_bounds__(128) void k_mod(const float* __restrict__ feat,
                                             const float* __restrict__ dw,
                                             const float* __restrict__ Wsh,
                                             const float* __restrict__ bsh,
                                             const float* __restrict__ Wex,
                                             const float* __restrict__ bex,
                                             float* __restrict__ mod) {
    int b = blockIdx.x, t = threadIdx.x;
    __shared__ float sm[128], ssh[64];
    {
        float full = g_red[0][b][t], row0 = g_red[1][b][t], row127 = g_red[2][b][t];
        float col0 = g_red[3][b][t], col127 = g_red[4][b][t];
        float x00 = g_corn[0][b][t], x0e = g_corn[1][b][t];
        float xe0 = g_corn[2][b][t], xee = g_corn[3][b][t];
        float acc = 0.0f;
#pragma unroll
        for (int kh = 0; kh < 3; ++kh)
#pragma unroll
            for (int kw = 0; kw < 3; ++kw) {
                int dh_ = kh - 1, dwv = kw - 1;
                float T = full;
                if (dh_ == -1) T -= row127;
                else if (dh_ == 1) T -= row0;
                if (dwv == -1) T -= col127;
                else if (dwv == 1) T -= col0;
                if (dh_ == -1 && dwv == -1) T += xee;
                if (dh_ == -1 && dwv == 1) T += xe0;
                if (dh_ == 1 && dwv == -1) T += x0e;
                if (dh_ == 1 && dwv == 1) T += x00;
                acc += dw[t * 9 + kh * 3 + kw] * T;
            }
        float spat = acc * (1.0f / 16384.0f);
        sm[t] = feat[b * 128 + t] * spat;
    }
    __syncthreads();
    if (t < 64) {
        float acc = bsh[t];
        for (int c = 0; c < 128; ++c) acc += sm[c] * Wsh[c * 64 + t];
        ssh[t] = geluf(acc);
    }
    __syncthreads();
    float acc = bex[t];
    for (int k = 0; k < 64; ++k) acc += ssh[k] * Wex[k * 128 + t];
    mod[b * 128 + t] = sigmf(acc);
}

// ---------- K4c: fold mod into per-b weights ----------
__global__ __launch_bounds__(256) void k_wmod(const float* __restrict__ mod) {
    int i = blockIdx.x * 256 + threadIdx.x;   // 16*147456 + 16*16384 = 2621440
    if (i < 2359296) {
        int b = i / 147456;
        int rem = i - b * 147456;
        int chunk = (rem >> 12) & 3;
        int cil = rem & 31;
        g_Wcb[i] = (f16)((float)g_Wc[rem] * mod[b * 128 + chunk * 32 + cil]);
    } else if (i < 2621440) {
        int j = i - 2359296;
        int b = j / 16384;
        int rem = j - b * 16384;
        int chunk = rem >> 12;
        int cil = rem & 31;
        g_Wscb[j] = (f16)((float)g_Wsc[rem] * mod[b * 128 + chunk * 32 + cil]);
    }
}

// ---------- K5 (MFMA): conv1 3x3 -> y1T f16 + bn1 stats ----------
// Double-buffered LDS x-tile via global_load_lds (deep MLP, no VGPR dests),
// XOR bank-swizzle applied on read with inverse-permuted global source (G21).
// Weights per-b (mod-folded) read as fragments from L2. One barrier per chunk.
__global__ __launch_bounds__(256, 3) void k_conv1m(float* __restrict__ stats) {
    int orig = blockIdx.x;
    int sw = (orig & 7) * 256 + (orig >> 3);   // bijective: 2048 % 8 == 0
    int h = sw & 127;
    int b = sw >> 7;
    int t = threadIdx.x;
    int lane = t & 63;
    int wv = t >> 6;
    int l15 = lane & 15, lg = lane >> 4;
    int co_half = (wv >> 1) * 64;
    int w_half = (wv & 1) * 64;

    __shared__ __align__(16) f16 xs[2][3][130][32];   // 2 x 24960 B

    f32x4 acc[4][4];
#pragma unroll
    for (int ct = 0; ct < 4; ++ct)
#pragma unroll
        for (int wt = 0; wt < 4; ++wt) acc[ct][wt] = (f32x4){0.f, 0.f, 0.f, 0.f};

    const f16* rowc[3];
#pragma unroll
    for (int r = 0; r < 3; ++r) {
        int hr = h + r - 1;
        rowc[r] = ((unsigned)hr < 128u) ? (g_xT + ((size_t)(b * 128 + hr)) * 4 * 4160)
                                        : (const f16*)0;
    }

    auto stage = [&](int c, int u) {
#pragma unroll
        for (int i = 0; i < 7; ++i) {
            int g = t + i * 256;
            if (g < 1560) {
                int r = g / 520;
                int p = g - r * 520;
                // inverse bank-swizzle on the SOURCE granule (involution)
                int q = (p & ~3) | ((p & 3) ^ ((p >> 3) & 3));
                const f16* src = rowc[r] ? (rowc[r] + c * 4160 + q * 8) : (g_zrow + q * 8);
                f16* dst = &xs[u][0][0][0] + (size_t)g * 8;
                __builtin_amdgcn_global_load_lds(
                    (const __attribute__((address_space(1))) unsigned int*)src,
                    (__attribute__((address_space(3))) unsigned int*)dst, 16, 0, 0);
            }
        }
    };

    stage(0, 0);
    __syncthreads();   // drains vmcnt -> buf0 ready

#pragma unroll
    for (int c = 0; c < 4; ++c) {
        const int u = c & 1;
        if (c < 3) stage(c + 1, u ^ 1);   // in flight under the MFMA phase

#pragma unroll
        for (int tap = 0; tap < 9; ++tap) {
            const int kh = tap / 3, kw = tap - kh * 3;
            f16x8 af[4], bf[4];
#pragma unroll
            for (int ct = 0; ct < 4; ++ct)
                af[ct] = *(const f16x8*)(g_Wcb + ((((size_t)b * 9 + tap) * 4 + c) * 128
                                                  + co_half + ct * 16 + l15) * 32 + lg * 8);
#pragma unroll
            for (int wt = 0; wt < 4; ++wt) {
                int s = w_half + wt * 16 + l15 + kw;
                bf[wt] = *(const f16x8*)&xs[u][kh][s][(lg ^ ((s >> 1) & 3)) * 8];
            }
#pragma unroll
            for (int ct = 0; ct < 4; ++ct)
#pragma unroll
                for (int wt = 0; wt < 4; ++wt)
                    acc[ct][wt] = __builtin_amdgcn_mfma_f32_16x16x32_f16(
                        af[ct], bf[wt], acc[ct][wt], 0, 0, 0);
        }
        __syncthreads();   // reads of buf u done; stage for c+1 drained
    }

    // ---- epilogue: write y1T (f16) + bn1 stats ----
#pragma unroll
    for (int ct = 0; ct < 4; ++ct) {
        int cog = (wv >> 1) * 2 + (ct >> 1);
        int col = (ct & 1) * 16 + lg * 4;
#pragma unroll
        for (int wt = 0; wt < 4; ++wt) {
            int w = w_half + wt * 16 + l15;
            f16x4 pk;
            pk[0] = (f16)acc[ct][wt][0];
            pk[1] = (f16)acc[ct][wt][1];
            pk[2] = (f16)acc[ct][wt][2];
            pk[3] = (f16)acc[ct][wt][3];
            *(f16x4*)(g_y1T + ((((size_t)(b * 128 + h)) * 4 + cog) * 128 + w) * 32 + col) = pk;
        }
#pragma unroll
        for (int r = 0; r < 4; ++r) {
            int co = co_half + ct * 16 + lg * 4 + r;
            float s = 0, q = 0;
#pragma unroll
            for (int wt = 0; wt < 4; ++wt) {
                float v = acc[ct][wt][r];
                s += v; q += v * v;
            }
#pragma unroll
            for (int o = 1; o < 16; o <<= 1) {
                s += __shfl_xor(s, o);
                q += __shfl_xor(q, o);
            }
            if (l15 == 0) {
                atomicAdd(&stats[co], s);
                atomicAdd(&stats[128 + co], q);
            }
        }
    }
}

// ---------- K6: finalize bn1 -> affine coefs ----------
__global__ __launch_bounds__(128) void k_fin1(const float* __restrict__ stats,
                                              const float* __restrict__ g1, const float* __restrict__ be1,
                                              float* __restrict__ coef) {
    int t = threadIdx.x;
    const float inv = 1.0f / NSTAT;
    float m = stats[t] * inv;
    float v = stats[128 + t] * inv - m * m;
    float a = g1[t] * rsqrtf(v + 1e-5f);
    coef[t] = a;
    coef[128 + t] = be1[t] - m * a;
}

// ---------- K7 (MFMA): conv2 (1x1) bn2-stats + sc (1x1) stats ----------
__global__ __launch_bounds__(256, 2) void k_conv2m(const float* __restrict__ coef,
                                                   float* __restrict__ stats) {
    int orig = blockIdx.x;
    int sw = (orig & 7) * 256 + (orig >> 3);
    int h = sw & 127;
    int b = sw >> 7;
    int t = threadIdx.x;
    int lane = t & 63;
    int wv = t >> 6;
    int l15 = lane & 15, lg = lane >> 4;
    int co_half = (wv >> 1) * 64;
    int w_half = (wv & 1) * 64;

    f32x4 acc[4][4], asc[4][4];
#pragma unroll
    for (int ct = 0; ct < 4; ++ct)
#pragma unroll
        for (int wt = 0; wt < 4; ++wt) {
            acc[ct][wt] = (f32x4){0.f, 0.f, 0.f, 0.f};
            asc[ct][wt] = (f32x4){0.f, 0.f, 0.f, 0.f};
        }

#pragma unroll
    for (int chunk = 0; chunk < 4; ++chunk) {
        float ca[8], cc[8];
#pragma unroll
        for (int j = 0; j < 8; ++j) {
            int ci = chunk * 32 + lg * 8 + j;
            ca[j] = coef[ci];
            cc[j] = coef[128 + ci];
        }
        f16x8 bfr[4], bx[4];
#pragma unroll
        for (int wt = 0; wt < 4; ++wt) {
            int w = w_half + wt * 16 + l15;
            f16x8 raw = *(const f16x8*)(g_y1T + ((((size_t)(b * 128 + h)) * 4 + chunk) * 128 + w) * 32 + lg * 8);
#pragma unroll
            for (int j = 0; j < 8; ++j) {
                float v = ca[j] * (float)raw[j] + cc[j];
                bfr[wt][j] = (f16)(v * sigmf(v));
            }
            bx[wt] = *(const f16x8*)(g_xT + (((size_t)(b * 128 + h)) * 4 + chunk) * 4160 + (w + 1) * 32 + lg * 8);
        }
        f16x8 af[4], sf[4];
#pragma unroll
        for (int ct = 0; ct < 4; ++ct) {
            af[ct] = *(const f16x8*)(g_W2 + ((size_t)chunk * 128 + co_half + ct * 16 + l15) * 32 + lg * 8);
            sf[ct] = *(const f16x8*)(g_Wscb + (((size_t)b * 4 + chunk) * 128 + co_half + ct * 16 + l15) * 32 + lg * 8);
        }
#pragma unroll
        for (int ct = 0; ct < 4; ++ct)
#pragma unroll
            for (int wt = 0; wt < 4; ++wt) {
                acc[ct][wt] = __builtin_amdgcn_mfma_f32_16x16x32_f16(
                    af[ct], bfr[wt], acc[ct][wt], 0, 0, 0);
                asc[ct][wt] = __builtin_amdgcn_mfma_f32_16x16x32_f16(
                    sf[ct], bx[wt], asc[ct][wt], 0, 0, 0);
            }
    }

#pragma unroll
    for (int ct = 0; ct < 4; ++ct) {
#pragma unroll
        for (int r = 0; r < 4; ++r) {
            int co = co_half + ct * 16 + lg * 4 + r;
            float s = 0, q = 0, ss = 0, qq = 0;
#pragma unroll
            for (int wt = 0; wt < 4; ++wt) {
                float v = acc[ct][wt][r];
                s += v; q += v * v;
                float u = asc[ct][wt][r];
                ss += u; qq += u * u;
            }
#pragma unroll
            for (int o = 1; o < 16; o <<= 1) {
                s += __shfl_xor(s, o);
                q += __shfl_xor(q, o);
                ss += __shfl_xor(ss, o);
                qq += __shfl_xor(qq, o);
            }
            if (l15 == 0) {
                atomicAdd(&stats[512 + co], s);
                atomicAdd(&stats[640 + co], q);
                atomicAdd(&stats[256 + co], ss);
                atomicAdd(&stats[384 + co], qq);
            }
        }
    }
}

// ---------- K8: finalize bn2 + bnsc ----------
__global__ __launch_bounds__(256) void k_fin2(const float* __restrict__ stats,
                                              const float* __restrict__ g2, const float* __restrict__ be2,
                                              const float* __restrict__ gsc, const float* __restrict__ bsc,
                                              float* __restrict__ coef) {
    int t = threadIdx.x;
    const float inv = 1.0f / NSTAT;
    if (t < 128) {
        float m = stats[512 + t] * inv;
        float v = stats[640 + t] * inv - m * m;
        float a = g2[t] * rsqrtf(v + 1e-5f);
        coef[512 + t] = a;
        coef[640 + t] = be2[t] - m * a;
    } else {
        int c = t - 128;
        float m = stats[256 + c] * inv;
        float v = stats[384 + c] * inv - m * m;
        float a = gsc[c] * rsqrtf(v + 1e-5f);
        coef[256 + c] = a;
        coef[384 + c] = bsc[c] - m * a;
    }
}

// ---------- K9 (MFMA): out = silu(bn2(conv2(silu(bn1(y1)))) + bnsc(sc(xm))) ----------
__global__ __launch_bounds__(256, 2) void k_final(float* __restrict__ out,
                                                  const float* __restrict__ coef) {
    int orig = blockIdx.x;
    int sw = (orig & 7) * 256 + (orig >> 3);
    int h = sw & 127;
    int b = sw >> 7;
    int t = threadIdx.x;
    int lane = t & 63;
    int wv = t >> 6;
    int l15 = lane & 15, lg = lane >> 4;
    int co_half = (wv >> 1) * 64;
    int w_half = (wv & 1) * 64;

    f32x4 acc[4][4], asc[4][4];
#pragma unroll
    for (int ct = 0; ct < 4; ++ct)
#pragma unroll
        for (int wt = 0; wt < 4; ++wt) {
            acc[ct][wt] = (f32x4){0.f, 0.f, 0.f, 0.f};
            asc[ct][wt] = (f32x4){0.f, 0.f, 0.f, 0.f};
        }

#pragma unroll
    for (int chunk = 0; chunk < 4; ++chunk) {
        float ca[8], cc[8];
#pragma unroll
        for (int j = 0; j < 8; ++j) {
            int ci = chunk * 32 + lg * 8 + j;
            ca[j] = coef[ci];
            cc[j] = coef[128 + ci];
        }
        f16x8 bf[4], bx[4], af[4], sf[4];
#pragma unroll
        for (int wt = 0; wt < 4; ++wt) {
            int w = w_half + wt * 16 + l15;
            f16x8 raw = *(const f16x8*)(g_y1T + ((((size_t)(b * 128 + h)) * 4 + chunk) * 128 + w) * 32 + lg * 8);
#pragma unroll
            for (int j = 0; j < 8; ++j) {
                float v = ca[j] * (float)raw[j] + cc[j];
                bf[wt][j] = (f16)(v * sigmf(v));
            }
            bx[wt] = *(const f16x8*)(g_xT + (((size_t)(b * 128 + h)) * 4 + chunk) * 4160 + (w + 1) * 32 + lg * 8);
        }
#pragma unroll
        for (int ct = 0; ct < 4; ++ct) {
            af[ct] = *(const f16x8*)(g_W2 + ((size_t)chunk * 128 + co_half + ct * 16 + l15) * 32 + lg * 8);
            sf[ct] = *(const f16x8*)(g_Wscb + (((size_t)b * 4 + chunk) * 128 + co_half + ct * 16 + l15) * 32 + lg * 8);
        }
#pragma unroll
        for (int ct = 0; ct < 4; ++ct)
#pragma unroll
            for (int wt = 0; wt < 4; ++wt) {
                acc[ct][wt] = __builtin_amdgcn_mfma_f32_16x16x32_f16(
                    af[ct], bf[wt], acc[ct][wt], 0, 0, 0);
                asc[ct][wt] = __builtin_amdgcn_mfma_f32_16x16x32_f16(
                    sf[ct], bx[wt], asc[ct][wt], 0, 0, 0);
            }
    }

#pragma unroll
    for (int ct = 0; ct < 4; ++ct) {
#pragma unroll
        for (int r = 0; r < 4; ++r) {
            int co = co_half + ct * 16 + lg * 4 + r;
            float a2 = coef[512 + co], c2 = coef[640 + co];
            float as = coef[256 + co], cs = coef[384 + co];
#pragma unroll
            for (int wt = 0; wt < 4; ++wt) {
                float v = a2 * acc[ct][wt][r] + c2 + as * asc[ct][wt][r] + cs;
                v = v * sigmf(v);
                out[(((size_t)b * 128 + co) * 128 + h) * 128 + w_half + wt * 16 + l15] = v;
            }
        }
    }
}

// ---------- launcher ----------
extern "C" void kernel_launch(void* const* d_in, const int* in_sizes, int n_in,
                              void* d_out, int out_size, void* d_ws, size_t ws_size,
                              hipStream_t stream) {
    (void)in_sizes; (void)n_in; (void)out_size; (void)ws_size;
    const float* x    = (const float*)d_in[0];
    const float* dce  = (const float*)d_in[1];
    const float* dwc  = (const float*)d_in[2];
    const float* W1   = (const float*)d_in[3];
    const float* b1   = (const float*)d_in[4];
    const float* W2d  = (const float*)d_in[5];
    const float* b2d  = (const float*)d_in[6];
    const float* Wsh  = (const float*)d_in[7];
    const float* bsh  = (const float*)d_in[8];
    const float* Wex  = (const float*)d_in[9];
    const float* bex  = (const float*)d_in[10];
    const float* c1w  = (const float*)d_in[11];
    const float* g1   = (const float*)d_in[12];
    const float* be1  = (const float*)d_in[13];
    const float* c2w  = (const float*)d_in[14];
    const float* g2   = (const float*)d_in[15];
    const float* be2  = (const float*)d_in[16];
    const float* scw  = (const float*)d_in[17];
    const float* gsc  = (const float*)d_in[18];
    const float* bsc  = (const float*)d_in[19];

    // scratch layout in d_ws (floats):
    // [0..2048) dh  [2048..2816) stats  [2816..3584) coef
    // [3584..5632) feat  [5632..7680) md
    float* F = (float*)d_ws;
    float* dh    = F;
    float* stats = F + 2048;
    float* coef  = F + 2816;
    float* feat  = F + 3584;
    float* md    = F + 5632;

    float* out = (float*)d_out;

    hipMemsetAsync(F, 0, 2816 * sizeof(float), stream);  // dh + stats

    k_wprep<<<704, 256, 0, stream>>>(c1w, scw, c2w);     // also zeroes g_red
    k_dce1<<<128, 256, 0, stream>>>(dce, W1, dh);
    k_dce2<<<16, 128, 0, stream>>>(dh, b1, W2d, b2d, feat);
    k_xprep<<<2048, 256, 0, stream>>>(x);                 // raw xT + spatial reductions
    k_mod<<<16, 128, 0, stream>>>(feat, dwc, Wsh, bsh, Wex, bex, md);
    k_wmod<<<10240, 256, 0, stream>>>(md);
    k_conv1m<<<2048, 256, 0, stream>>>(stats);
    k_fin1<<<1, 128, 0, stream>>>(stats, g1, be1, coef);
    k_conv2m<<<2048, 256, 0, stream>>>(coef, stats);
    k_fin2<<<1, 256, 0, stream>>>(stats, g2, be2, gsc, bsc, coef);
    k_final<<<2048, 256, 0, stream>>>(out, coef);
}